// Round 12
// baseline (2151.091 us; speedup 1.0000x reference)
//
#include <hip/hip_runtime.h>
#include <math.h>

#define BATCH 4096
#define NPART 100
#define PSZ   64

__device__ __forceinline__ void fma4(float4& d, const float s, const float4 v) {
    d.x = fmaf(s, v.x, d.x); d.y = fmaf(s, v.y, d.y);
    d.z = fmaf(s, v.z, d.z); d.w = fmaf(s, v.w, d.w);
}
__device__ __forceinline__ float4 addrelu4(const float4 a, const float4 b) {
    return make_float4(fmaxf(a.x + b.x, 0.f), fmaxf(a.y + b.y, 0.f),
                       fmaxf(a.z + b.z, 0.f), fmaxf(a.w + b.w, 0.f));
}

// async global->LDS, 16B per lane. LDS dest is WAVE-UNIFORM base
// (HW adds lane*16); global src is per-lane.
typedef const __attribute__((address_space(1))) unsigned int  gu32;
typedef __attribute__((address_space(3)))       unsigned int  lu32;
__device__ __forceinline__ void gload_lds16(const float* g, float* l) {
    __builtin_amdgcn_global_load_lds((gu32*)g, (lu32*)l, 16, 0, 0);
}

// Stage one 4096-float (16KB) panel into LDS (k_lstm layer weights).
__device__ __forceinline__ void stage_panel16(const float* __restrict__ w,
                                              float* dst, const int p,
                                              const int wv, const int lane) {
    const float* g = w + p * 4096 + wv * 256 + lane * 4;
    float*       l = dst + wv * 256;            // wave-uniform LDS base
    #pragma unroll
    for (int s = 0; s < 4; ++s)
        gload_lds16(g + s * 1024, l + s * 1024);
}

// Stage one 2048-float (8KB) panel into LDS (encoder W2 8-row panels).
// Per wave: 2 async loads covering floats [wv*512, wv*512+512).
__device__ __forceinline__ void stage_panel8(const float* __restrict__ w,
                                             float* dst, const int p,
                                             const int wv, const int lane) {
    const float* g = w + p * 2048 + wv * 512 + lane * 4;
    float*       l = dst + wv * 512;            // wave-uniform LDS base
    gload_lds16(g,       l);
    gload_lds16(g + 256, l + 256);
}

// ------------------------------------------------------------------
// Encoder chunk worker v13: same W2-from-LDS structure as v8 (R6:
// 1468->1246us) but 8-row panels (2x8KB dbuf instead of 2x16KB), so
// total LDS drops 66KB -> 49.7KB -> 3 blocks/CU (was 2). Occupancy
// is the measured limiter (VALUBusy 58% @ 23% occ); the 3rd block
// fills barrier/lgkm bubbles. Barrier count per chunk 17->33; R2-R5
// showed barriers are cheap when other blocks can run through them.
// ------------------------------------------------------------------
template<int NRR>
__device__ __forceinline__ void enc_chunk(
    const float* __restrict__ xb, const int rbase,
    const float* __restrict__ w1c, const float* __restrict__ w2,
    float* __restrict__ h1s, float* __restrict__ wpan,
    const int wv, const int lane, const int rg, const int col0,
    const float4 b1a, const float4 b1b, const float4 b2a, const float4 b2b,
    float* msum)
{
    stage_panel8(w2, wpan, 0, wv, lane);

    int rowr[NRR];
    #pragma unroll
    for (int rr = 0; rr < NRR; ++rr)
        rowr[rr] = rbase + ((NRR == 1 && rg >= 4) ? 0 : (rg + 8 * rr));

    // ---- fc1: h1 = relu(x @ W1 + b1), K=64, x and W1 from global
    float4 a0[NRR], a1[NRR];
    #pragma unroll
    for (int rr = 0; rr < NRR; ++rr) {
        a0[rr] = make_float4(0.f, 0.f, 0.f, 0.f);
        a1[rr] = make_float4(0.f, 0.f, 0.f, 0.f);
    }
    #pragma unroll 2
    for (int k0 = 0; k0 < 64; k0 += 4) {
        float4 bva[4], bvb[4];
        #pragma unroll
        for (int kk = 0; kk < 4; ++kk) {
            bva[kk] = *(const float4*)(w1c + (k0 + kk) * 256);
            bvb[kk] = *(const float4*)(w1c + (k0 + kk) * 256 + 4);
        }
        #pragma unroll
        for (int rr = 0; rr < NRR; ++rr) {
            const float4 av = *(const float4*)(xb + (size_t)rowr[rr] * 64 + k0);
            fma4(a0[rr], av.x, bva[0]); fma4(a0[rr], av.y, bva[1]);
            fma4(a0[rr], av.z, bva[2]); fma4(a0[rr], av.w, bva[3]);
            fma4(a1[rr], av.x, bvb[0]); fma4(a1[rr], av.y, bvb[1]);
            fma4(a1[rr], av.z, bvb[2]); fma4(a1[rr], av.w, bvb[3]);
        }
    }
    #pragma unroll
    for (int rr = 0; rr < NRR; ++rr) {
        const int r = rg + 8 * rr;
        *(float4*)&h1s[r * 260 + col0]     = addrelu4(a0[rr], b1a);
        *(float4*)&h1s[r * 260 + col0 + 4] = addrelu4(a1[rr], b1b);
    }
    __syncthreads();   // h1s visible + panel 0 landed

    // ---- fc2: K=256 as 32 panels of 8; W from LDS, double-buffered
    float4 c0[NRR], c1[NRR];
    #pragma unroll
    for (int rr = 0; rr < NRR; ++rr) {
        c0[rr] = make_float4(0.f, 0.f, 0.f, 0.f);
        c1[rr] = make_float4(0.f, 0.f, 0.f, 0.f);
    }
    #pragma unroll 1
    for (int p = 0; p < 32; ++p) {
        if (p < 31)
            stage_panel8(w2, wpan + ((p + 1) & 1) * 2048, p + 1, wv, lane);
        const float* wp = wpan + (p & 1) * 2048;
        #pragma unroll
        for (int it = 0; it < 2; ++it) {
            const int kk0 = it * 4;
            float4 bva[4], bvb[4];
            #pragma unroll
            for (int kk = 0; kk < 4; ++kk) {
                bva[kk] = *(const float4*)&wp[(kk0 + kk) * 256 + col0];
                bvb[kk] = *(const float4*)&wp[(kk0 + kk) * 256 + col0 + 4];
            }
            const int kg = p * 8 + kk0;
            #pragma unroll
            for (int rr = 0; rr < NRR; ++rr) {
                const float4 av = *(const float4*)&h1s[(rg + 8 * rr) * 260 + kg];
                fma4(c0[rr], av.x, bva[0]); fma4(c0[rr], av.y, bva[1]);
                fma4(c0[rr], av.z, bva[2]); fma4(c0[rr], av.w, bva[3]);
                fma4(c1[rr], av.x, bvb[0]); fma4(c1[rr], av.y, bvb[1]);
                fma4(c1[rr], av.z, bvb[2]); fma4(c1[rr], av.w, bvb[3]);
            }
        }
        __syncthreads();
    }

    #pragma unroll
    for (int rr = 0; rr < NRR; ++rr) {
        if (NRR == 4 || rg < 4) {
            msum[0] += fmaxf(c0[rr].x + b2a.x, 0.f);
            msum[1] += fmaxf(c0[rr].y + b2a.y, 0.f);
            msum[2] += fmaxf(c0[rr].z + b2a.z, 0.f);
            msum[3] += fmaxf(c0[rr].w + b2a.w, 0.f);
            msum[4] += fmaxf(c1[rr].x + b2b.x, 0.f);
            msum[5] += fmaxf(c1[rr].y + b2b.y, 0.f);
            msum[6] += fmaxf(c1[rr].z + b2b.z, 0.f);
            msum[7] += fmaxf(c1[rr].w + b2b.w, 0.f);
        }
    }
}

// ------------------------------------------------------------------
// Kernel 1: particle encoder. v13: 8-row W2 panels -> 49.7KB LDS ->
// 3 blocks/CU. No launch-bounds min-waves hint (R2/R3: hints spill).
// ------------------------------------------------------------------
__global__ __launch_bounds__(256) void k_encoder(
    const float* __restrict__ x,
    const float* __restrict__ w1, const float* __restrict__ b1,
    const float* __restrict__ w2, const float* __restrict__ b2,
    float* __restrict__ xp)
{
    __shared__ __align__(16) float h1s[32 * 260];      // 33280 B
    __shared__ __align__(16) float wpan[2 * 8 * 256];  // 16384 B
    const int tid  = threadIdx.x;
    const int b    = blockIdx.x;
    const int lane = tid & 63;
    const int wv   = tid >> 6;
    const int cgw  = lane & 7;
    const int rg   = lane >> 3;
    const int col0 = wv * 64 + cgw * 8;

    const float* xb  = x + (size_t)b * (NPART * PSZ);
    const float* w1c = w1 + col0;
    const float4 b1a = *(const float4*)&b1[col0];
    const float4 b1b = *(const float4*)&b1[col0 + 4];
    const float4 b2a = *(const float4*)&b2[col0];
    const float4 b2b = *(const float4*)&b2[col0 + 4];

    float msum[8] = {0.f,0.f,0.f,0.f,0.f,0.f,0.f,0.f};

    enc_chunk<4>(xb,  0, w1c, w2, h1s, wpan, wv, lane, rg, col0, b1a, b1b, b2a, b2b, msum);
    enc_chunk<4>(xb, 32, w1c, w2, h1s, wpan, wv, lane, rg, col0, b1a, b1b, b2a, b2b, msum);
    enc_chunk<4>(xb, 64, w1c, w2, h1s, wpan, wv, lane, rg, col0, b1a, b1b, b2a, b2b, msum);
    enc_chunk<1>(xb, 96, w1c, w2, h1s, wpan, wv, lane, rg, col0, b1a, b1b, b2a, b2b, msum);

    #pragma unroll
    for (int q = 0; q < 8; ++q) {
        msum[q] += __shfl_xor(msum[q], 8, 64);
        msum[q] += __shfl_xor(msum[q], 16, 64);
        msum[q] += __shfl_xor(msum[q], 32, 64);
    }
    if (rg == 0) {
        float4 o0 = make_float4(msum[0] / 100.f, msum[1] / 100.f,
                                msum[2] / 100.f, msum[3] / 100.f);
        float4 o1 = make_float4(msum[4] / 100.f, msum[5] / 100.f,
                                msum[6] / 100.f, msum[7] / 100.f);
        *(float4*)&xp[(size_t)b * 256 + col0]     = o0;
        *(float4*)&xp[(size_t)b * 256 + col0 + 4] = o1;
    }
}

// ------------------------------------------------------------------
// Kernel 2: fc3..fc6 fused MLP, 8 rows per block (512 blocks)
// ------------------------------------------------------------------
__global__ __launch_bounds__(256) void k_mlp(
    const float* __restrict__ cin, const float* __restrict__ xp,
    const float* __restrict__ w3, const float* __restrict__ b3,
    const float* __restrict__ w4, const float* __restrict__ b4,
    const float* __restrict__ w5, const float* __restrict__ b5,
    const float* __restrict__ w6, const float* __restrict__ b6,
    float* __restrict__ z)
{
    __shared__ float in0[8][320];
    __shared__ float h3[8][512];
    __shared__ float h4[8][256];
    __shared__ float h5[8][128];
    const int tid  = threadIdx.x;
    const int row0 = blockIdx.x * 8;

    for (int i = tid; i < 8 * 16; i += 256) {
        int r = i >> 4, q = i & 15;
        *(float4*)&in0[r][q * 4] = *(const float4*)&cin[(size_t)(row0 + r) * 64 + q * 4];
    }
    for (int i = tid; i < 8 * 64; i += 256) {
        int r = i >> 6, q = i & 63;
        *(float4*)&in0[r][64 + q * 4] = *(const float4*)&xp[(size_t)(row0 + r) * 256 + q * 4];
    }
    __syncthreads();

    {
        float a0[8], a1[8];
        #pragma unroll
        for (int r = 0; r < 8; ++r) { a0[r] = 0.f; a1[r] = 0.f; }
        const int c0 = tid, c1 = tid + 256;
        for (int kq = 0; kq < 80; ++kq) {
            const int k0 = kq * 4;
            float wa0 = w3[(k0+0)*512 + c0], wa1 = w3[(k0+1)*512 + c0];
            float wa2 = w3[(k0+2)*512 + c0], wa3 = w3[(k0+3)*512 + c0];
            float wb0 = w3[(k0+0)*512 + c1], wb1 = w3[(k0+1)*512 + c1];
            float wb2 = w3[(k0+2)*512 + c1], wb3 = w3[(k0+3)*512 + c1];
            #pragma unroll
            for (int r = 0; r < 8; ++r) {
                const float4 a = *(const float4*)&in0[r][k0];
                a0[r] = fmaf(a.x, wa0, fmaf(a.y, wa1, fmaf(a.z, wa2, fmaf(a.w, wa3, a0[r]))));
                a1[r] = fmaf(a.x, wb0, fmaf(a.y, wb1, fmaf(a.z, wb2, fmaf(a.w, wb3, a1[r]))));
            }
        }
        const float bb0 = b3[c0], bb1 = b3[c1];
        #pragma unroll
        for (int r = 0; r < 8; ++r) {
            h3[r][c0] = fmaxf(a0[r] + bb0, 0.f);
            h3[r][c1] = fmaxf(a1[r] + bb1, 0.f);
        }
    }
    __syncthreads();

    {
        float ac[8];
        #pragma unroll
        for (int r = 0; r < 8; ++r) ac[r] = 0.f;
        for (int kq = 0; kq < 128; ++kq) {
            const int k0 = kq * 4;
            float w0 = w4[(k0+0)*256 + tid], w1v = w4[(k0+1)*256 + tid];
            float w2v = w4[(k0+2)*256 + tid], w3v = w4[(k0+3)*256 + tid];
            #pragma unroll
            for (int r = 0; r < 8; ++r) {
                const float4 a = *(const float4*)&h3[r][k0];
                ac[r] = fmaf(a.x, w0, fmaf(a.y, w1v, fmaf(a.z, w2v, fmaf(a.w, w3v, ac[r]))));
            }
        }
        const float bb = b4[tid];
        #pragma unroll
        for (int r = 0; r < 8; ++r) h4[r][tid] = fmaxf(ac[r] + bb, 0.f);
    }
    __syncthreads();

    {
        const int c5 = tid & 127, half = tid >> 7;
        float ac[4];
        #pragma unroll
        for (int r = 0; r < 4; ++r) ac[r] = 0.f;
        for (int kq = 0; kq < 64; ++kq) {
            const int k0 = kq * 4;
            float w0 = w5[(k0+0)*128 + c5], w1v = w5[(k0+1)*128 + c5];
            float w2v = w5[(k0+2)*128 + c5], w3v = w5[(k0+3)*128 + c5];
            #pragma unroll
            for (int r = 0; r < 4; ++r) {
                const float4 a = *(const float4*)&h4[half * 4 + r][k0];
                ac[r] = fmaf(a.x, w0, fmaf(a.y, w1v, fmaf(a.z, w2v, fmaf(a.w, w3v, ac[r]))));
            }
        }
        const float bb = b5[c5];
        #pragma unroll
        for (int r = 0; r < 4; ++r) h5[half * 4 + r][c5] = fmaxf(ac[r] + bb, 0.f);
    }
    __syncthreads();

    {
        const int c6 = tid & 31, r = tid >> 5;
        float ac = 0.f;
        for (int kq = 0; kq < 32; ++kq) {
            const int k0 = kq * 4;
            float w0 = w6[(k0+0)*32 + c6], w1v = w6[(k0+1)*32 + c6];
            float w2v = w6[(k0+2)*32 + c6], w3v = w6[(k0+3)*32 + c6];
            const float4 a = *(const float4*)&h5[r][k0];
            ac = fmaf(a.x, w0, fmaf(a.y, w1v, fmaf(a.z, w2v, fmaf(a.w, w3v, ac))));
        }
        z[(size_t)(row0 + r) * 32 + c6] = fmaxf(ac + b6[c6], 0.f);
    }
}

// ------------------------------------------------------------------
// Kernel 3: persistent LSTM (R11-validated v12, untouched): active
// layer's wih/whh staged in LDS via global_load_lds, v10 lane tile.
// ------------------------------------------------------------------
__global__ __launch_bounds__(256) void k_lstm(
    const float* __restrict__ z,
    const float* __restrict__ hid0, const float* __restrict__ cel0,
    const float* __restrict__ wih, const float* __restrict__ whh,
    const float* __restrict__ bih, const float* __restrict__ bhh,
    const float* __restrict__ w10, const float* __restrict__ b10,
    int* __restrict__ out)
{
    __shared__ float xs[8][32];
    __shared__ float hs[6][8][32];
    __shared__ float cs[6][8][32];
    __shared__ float gates[8][128];
    __shared__ float logits[8][361];
    __shared__ __align__(16) float wldsI[32 * 128];   // 16 KB, layer-resident
    __shared__ __align__(16) float wldsH[32 * 128];   // 16 KB
    const int tid  = threadIdx.x;
    const int row0 = blockIdx.x * 8;
    const int lane = tid & 63, wv = tid >> 6;

    stage_panel16(wih, wldsI, 0, wv, lane);
    stage_panel16(whh, wldsH, 0, wv, lane);

    for (int i = tid; i < 8 * 32; i += 256) xs[0][i] = z[(size_t)row0 * 32 + i];
    for (int i = tid; i < 6 * 8 * 32; i += 256) {
        int l = i >> 8, rj = i & 255;
        (&hs[0][0][0])[i] = hid0[(size_t)l * BATCH * 32 + (size_t)row0 * 32 + rj];
        (&cs[0][0][0])[i] = cel0[(size_t)l * BATCH * 32 + (size_t)row0 * 32 + rj];
    }
    __syncthreads();   // state visible + layer-0 W staged

    const int g  = tid & 127, rg = tid >> 7;
    const int jc = tid & 31,  jr = tid >> 5;

    for (int t = 0; t < 24; ++t) {
        for (int l = 0; l < 6; ++l) {
            const float* inp = (l == 0) ? ((t == 0) ? &xs[0][0] : &hs[5][0][0])
                                        : &hs[l - 1][0][0];
            const float bsum = bih[l * 128 + g] + bhh[l * 128 + g];
            float acc[4] = {bsum, bsum, bsum, bsum};
            #pragma unroll
            for (int k = 0; k < 32; k += 4) {
                float wi0 = wldsI[(k+0)*128 + g], wi1 = wldsI[(k+1)*128 + g];
                float wi2 = wldsI[(k+2)*128 + g], wi3 = wldsI[(k+3)*128 + g];
                float wh0 = wldsH[(k+0)*128 + g], wh1 = wldsH[(k+1)*128 + g];
                float wh2 = wldsH[(k+2)*128 + g], wh3 = wldsH[(k+3)*128 + g];
                #pragma unroll
                for (int rr = 0; rr < 4; ++rr) {
                    const int r = rg * 4 + rr;
                    const float4 ai = *(const float4*)&inp[r * 32 + k];
                    const float4 ah = *(const float4*)&hs[l][r][k];
                    acc[rr] = fmaf(ai.x, wi0, acc[rr]); acc[rr] = fmaf(ai.y, wi1, acc[rr]);
                    acc[rr] = fmaf(ai.z, wi2, acc[rr]); acc[rr] = fmaf(ai.w, wi3, acc[rr]);
                    acc[rr] = fmaf(ah.x, wh0, acc[rr]); acc[rr] = fmaf(ah.y, wh1, acc[rr]);
                    acc[rr] = fmaf(ah.z, wh2, acc[rr]); acc[rr] = fmaf(ah.w, wh3, acc[rr]);
                }
            }
            #pragma unroll
            for (int rr = 0; rr < 4; ++rr) gates[rg * 4 + rr][g] = acc[rr];
            __syncthreads();   // all wlds reads done + gates visible

            {
                const int ln = (l + 1) % 6;
                stage_panel16(wih, wldsI, ln, wv, lane);
                stage_panel16(whh, wldsH, ln, wv, lane);
            }

            {
                const float gi = gates[jr][jc],      gf = gates[jr][32 + jc];
                const float gg = gates[jr][64 + jc], go = gates[jr][96 + jc];
                const float i_ = 1.f / (1.f + expf(-gi));
                const float f_ = 1.f / (1.f + expf(-gf));
                const float o_ = 1.f / (1.f + expf(-go));
                const float g_ = tanhf(gg);
                const float cn = f_ * cs[l][jr][jc] + i_ * g_;
                cs[l][jr][jc] = cn;
                hs[l][jr][jc] = o_ * tanhf(cn);
            }
            __syncthreads();   // h/c visible + next-layer W staged
        }

        // ---- fc10 (w10: [k][361], L2-hot; runs 24x not 144x)
        #pragma unroll
        for (int pass = 0; pass < 2; ++pass) {
            const int v = tid + pass * 256;
            if (v < 361) {
                const float bb = b10[v];
                float a8[8];
                #pragma unroll
                for (int r = 0; r < 8; ++r) a8[r] = bb;
                #pragma unroll
                for (int k = 0; k < 32; k += 4) {
                    float w0 = w10[(k+0)*361 + v], w1v = w10[(k+1)*361 + v];
                    float w2v = w10[(k+2)*361 + v], w3v = w10[(k+3)*361 + v];
                    #pragma unroll
                    for (int r = 0; r < 8; ++r) {
                        const float4 a = *(const float4*)&hs[5][r][k];
                        a8[r] = fmaf(a.x, w0, fmaf(a.y, w1v, fmaf(a.z, w2v, fmaf(a.w, w3v, a8[r]))));
                    }
                }
                #pragma unroll
                for (int r = 0; r < 8; ++r) logits[r][v] = a8[r];
            }
        }
        __syncthreads();

        // ---- top-8 per row; one wave handles 2 rows.
        for (int rr = 0; rr < 2; ++rr) {
            const int r = wv * 2 + rr;
            float val[6];
            #pragma unroll
            for (int s = 0; s < 6; ++s) {
                const int v = lane + 64 * s;
                val[s] = (v < 361) ? logits[r][v] : -3.4e38f;
            }
            unsigned msk = 0x3Fu;
            const int rowg = row0 + r;
            for (int sel = 0; sel < 8; ++sel) {
                float bv = -3.4e38f; int bi = 0x7FFFFFFF;
                #pragma unroll
                for (int s = 0; s < 6; ++s) {
                    if (msk & (1u << s)) {
                        const float v2 = val[s]; const int i2 = lane + 64 * s;
                        if (v2 > bv || (v2 == bv && i2 < bi)) { bv = v2; bi = i2; }
                    }
                }
                #pragma unroll
                for (int off = 32; off >= 1; off >>= 1) {
                    const float ov = __shfl_xor(bv, off, 64);
                    const int   oi = __shfl_xor(bi, off, 64);
                    if (ov > bv || (ov == bv && oi < bi)) { bv = ov; bi = oi; }
                }
                if ((bi & 63) == lane) msk &= ~(1u << (bi >> 6));
                if (lane == 0) out[(size_t)rowg * 192 + t * 8 + sel] = bi;
            }
        }
        __syncthreads();
    }
}

// ------------------------------------------------------------------
extern "C" void kernel_launch(void* const* d_in, const int* in_sizes, int n_in,
                              void* d_out, int out_size, void* d_ws, size_t ws_size,
                              hipStream_t stream) {
    const float* cin  = (const float*)d_in[0];
    const float* x    = (const float*)d_in[1];
    const float* hid0 = (const float*)d_in[2];
    const float* cel0 = (const float*)d_in[3];
    const float* w1 = (const float*)d_in[4];  const float* b1 = (const float*)d_in[5];
    const float* w2 = (const float*)d_in[6];  const float* b2 = (const float*)d_in[7];
    const float* w3 = (const float*)d_in[8];  const float* b3 = (const float*)d_in[9];
    const float* w4 = (const float*)d_in[10]; const float* b4 = (const float*)d_in[11];
    const float* w5 = (const float*)d_in[12]; const float* b5 = (const float*)d_in[13];
    const float* w6 = (const float*)d_in[14]; const float* b6 = (const float*)d_in[15];
    const float* wih = (const float*)d_in[16]; const float* whh = (const float*)d_in[17];
    const float* bih = (const float*)d_in[18]; const float* bhh = (const float*)d_in[19];
    const float* w10 = (const float*)d_in[20]; const float* b10 = (const float*)d_in[21];

    float* xp = (float*)d_ws;                       // 4096 x 256
    float* zz = xp + (size_t)BATCH * 256;           // 4096 x 32
    int*   out = (int*)d_out;

    k_encoder<<<BATCH, 256, 0, stream>>>(x, w1, b1, w2, b2, xp);
    k_mlp<<<BATCH / 8, 256, 0, stream>>>(cin, xp, w3, b3, w4, b4, w5, b5, w6, b6, zz);
    k_lstm<<<BATCH / 8, 256, 0, stream>>>(zz, hid0, cel0, wih, whh, bih, bhh, w10, b10, out);
}

// Round 13
// 2140.703 us; speedup vs baseline: 1.0049x; 1.0049x over previous
//
#include <hip/hip_runtime.h>
#include <math.h>

#define BATCH 4096
#define NPART 100
#define PSZ   64

__device__ __forceinline__ void fma4(float4& d, const float s, const float4 v) {
    d.x = fmaf(s, v.x, d.x); d.y = fmaf(s, v.y, d.y);
    d.z = fmaf(s, v.z, d.z); d.w = fmaf(s, v.w, d.w);
}
__device__ __forceinline__ float4 addrelu4(const float4 a, const float4 b) {
    return make_float4(fmaxf(a.x + b.x, 0.f), fmaxf(a.y + b.y, 0.f),
                       fmaxf(a.z + b.z, 0.f), fmaxf(a.w + b.w, 0.f));
}

// async global->LDS, 16B per lane. LDS dest is WAVE-UNIFORM base
// (HW adds lane*16); global src is per-lane.
typedef const __attribute__((address_space(1))) unsigned int  gu32;
typedef __attribute__((address_space(3)))       unsigned int  lu32;
__device__ __forceinline__ void gload_lds16(const float* g, float* l) {
    __builtin_amdgcn_global_load_lds((gu32*)g, (lu32*)l, 16, 0, 0);
}

// Stage one 4096-float (16KB) panel into LDS, linear layout preserved.
__device__ __forceinline__ void stage_panel16(const float* __restrict__ w,
                                              float* dst, const int p,
                                              const int wv, const int lane) {
    const float* g = w + p * 4096 + wv * 256 + lane * 4;
    float*       l = dst + wv * 256;            // wave-uniform LDS base
    #pragma unroll
    for (int s = 0; s < 4; ++s)
        gload_lds16(g + s * 1024, l + s * 1024);
}

// ------------------------------------------------------------------
// Encoder chunk worker v8 (measured best: 1237-1246us, R6/R11/R8).
// fc2's W2 from LDS k-panels (16x256, double-buffered, global_load_lds).
// R12 evidence: occupancy is VGPR-pinned at ~2 waves/SIMD regardless of
// LDS (25-66KB all 23%); 8-row panels only diluted VALUBusy. Revert.
// ------------------------------------------------------------------
template<int NRR>
__device__ __forceinline__ void enc_chunk(
    const float* __restrict__ xb, const int rbase,
    const float* __restrict__ w1c, const float* __restrict__ w2,
    float* __restrict__ h1s, float* __restrict__ wpan,
    const int wv, const int lane, const int rg, const int col0,
    const float4 b1a, const float4 b1b, const float4 b2a, const float4 b2b,
    float* msum)
{
    stage_panel16(w2, wpan, 0, wv, lane);

    int rowr[NRR];
    #pragma unroll
    for (int rr = 0; rr < NRR; ++rr)
        rowr[rr] = rbase + ((NRR == 1 && rg >= 4) ? 0 : (rg + 8 * rr));

    // ---- fc1: h1 = relu(x @ W1 + b1), K=64, x and W1 from global
    float4 a0[NRR], a1[NRR];
    #pragma unroll
    for (int rr = 0; rr < NRR; ++rr) {
        a0[rr] = make_float4(0.f, 0.f, 0.f, 0.f);
        a1[rr] = make_float4(0.f, 0.f, 0.f, 0.f);
    }
    #pragma unroll 2
    for (int k0 = 0; k0 < 64; k0 += 4) {
        float4 bva[4], bvb[4];
        #pragma unroll
        for (int kk = 0; kk < 4; ++kk) {
            bva[kk] = *(const float4*)(w1c + (k0 + kk) * 256);
            bvb[kk] = *(const float4*)(w1c + (k0 + kk) * 256 + 4);
        }
        #pragma unroll
        for (int rr = 0; rr < NRR; ++rr) {
            const float4 av = *(const float4*)(xb + (size_t)rowr[rr] * 64 + k0);
            fma4(a0[rr], av.x, bva[0]); fma4(a0[rr], av.y, bva[1]);
            fma4(a0[rr], av.z, bva[2]); fma4(a0[rr], av.w, bva[3]);
            fma4(a1[rr], av.x, bvb[0]); fma4(a1[rr], av.y, bvb[1]);
            fma4(a1[rr], av.z, bvb[2]); fma4(a1[rr], av.w, bvb[3]);
        }
    }
    #pragma unroll
    for (int rr = 0; rr < NRR; ++rr) {
        const int r = rg + 8 * rr;
        *(float4*)&h1s[r * 260 + col0]     = addrelu4(a0[rr], b1a);
        *(float4*)&h1s[r * 260 + col0 + 4] = addrelu4(a1[rr], b1b);
    }
    __syncthreads();   // h1s visible + panel 0 landed

    // ---- fc2: K=256 as 16 panels of 16; W from LDS, double-buffered
    float4 c0[NRR], c1[NRR];
    #pragma unroll
    for (int rr = 0; rr < NRR; ++rr) {
        c0[rr] = make_float4(0.f, 0.f, 0.f, 0.f);
        c1[rr] = make_float4(0.f, 0.f, 0.f, 0.f);
    }
    #pragma unroll 1
    for (int p = 0; p < 16; ++p) {
        if (p < 15)
            stage_panel16(w2, wpan + ((p + 1) & 1) * 4096, p + 1, wv, lane);
        const float* wp = wpan + (p & 1) * 4096;
        #pragma unroll
        for (int it = 0; it < 4; ++it) {
            const int kk0 = it * 4;
            float4 bva[4], bvb[4];
            #pragma unroll
            for (int kk = 0; kk < 4; ++kk) {
                bva[kk] = *(const float4*)&wp[(kk0 + kk) * 256 + col0];
                bvb[kk] = *(const float4*)&wp[(kk0 + kk) * 256 + col0 + 4];
            }
            const int kg = p * 16 + kk0;
            #pragma unroll
            for (int rr = 0; rr < NRR; ++rr) {
                const float4 av = *(const float4*)&h1s[(rg + 8 * rr) * 260 + kg];
                fma4(c0[rr], av.x, bva[0]); fma4(c0[rr], av.y, bva[1]);
                fma4(c0[rr], av.z, bva[2]); fma4(c0[rr], av.w, bva[3]);
                fma4(c1[rr], av.x, bvb[0]); fma4(c1[rr], av.y, bvb[1]);
                fma4(c1[rr], av.z, bvb[2]); fma4(c1[rr], av.w, bvb[3]);
            }
        }
        __syncthreads();
    }

    #pragma unroll
    for (int rr = 0; rr < NRR; ++rr) {
        if (NRR == 4 || rg < 4) {
            msum[0] += fmaxf(c0[rr].x + b2a.x, 0.f);
            msum[1] += fmaxf(c0[rr].y + b2a.y, 0.f);
            msum[2] += fmaxf(c0[rr].z + b2a.z, 0.f);
            msum[3] += fmaxf(c0[rr].w + b2a.w, 0.f);
            msum[4] += fmaxf(c1[rr].x + b2b.x, 0.f);
            msum[5] += fmaxf(c1[rr].y + b2b.y, 0.f);
            msum[6] += fmaxf(c1[rr].z + b2b.z, 0.f);
            msum[7] += fmaxf(c1[rr].w + b2b.w, 0.f);
        }
    }
}

// ------------------------------------------------------------------
// Kernel 1: particle encoder (v8, measured best — reverted from v13).
// ------------------------------------------------------------------
__global__ __launch_bounds__(256) void k_encoder(
    const float* __restrict__ x,
    const float* __restrict__ w1, const float* __restrict__ b1,
    const float* __restrict__ w2, const float* __restrict__ b2,
    float* __restrict__ xp)
{
    __shared__ __align__(16) float h1s[32 * 260];       // 33280 B
    __shared__ __align__(16) float wpan[2 * 16 * 256];  // 32768 B
    const int tid  = threadIdx.x;
    const int b    = blockIdx.x;
    const int lane = tid & 63;
    const int wv   = tid >> 6;
    const int cgw  = lane & 7;
    const int rg   = lane >> 3;
    const int col0 = wv * 64 + cgw * 8;

    const float* xb  = x + (size_t)b * (NPART * PSZ);
    const float* w1c = w1 + col0;
    const float4 b1a = *(const float4*)&b1[col0];
    const float4 b1b = *(const float4*)&b1[col0 + 4];
    const float4 b2a = *(const float4*)&b2[col0];
    const float4 b2b = *(const float4*)&b2[col0 + 4];

    float msum[8] = {0.f,0.f,0.f,0.f,0.f,0.f,0.f,0.f};

    enc_chunk<4>(xb,  0, w1c, w2, h1s, wpan, wv, lane, rg, col0, b1a, b1b, b2a, b2b, msum);
    enc_chunk<4>(xb, 32, w1c, w2, h1s, wpan, wv, lane, rg, col0, b1a, b1b, b2a, b2b, msum);
    enc_chunk<4>(xb, 64, w1c, w2, h1s, wpan, wv, lane, rg, col0, b1a, b1b, b2a, b2b, msum);
    enc_chunk<1>(xb, 96, w1c, w2, h1s, wpan, wv, lane, rg, col0, b1a, b1b, b2a, b2b, msum);

    #pragma unroll
    for (int q = 0; q < 8; ++q) {
        msum[q] += __shfl_xor(msum[q], 8, 64);
        msum[q] += __shfl_xor(msum[q], 16, 64);
        msum[q] += __shfl_xor(msum[q], 32, 64);
    }
    if (rg == 0) {
        float4 o0 = make_float4(msum[0] / 100.f, msum[1] / 100.f,
                                msum[2] / 100.f, msum[3] / 100.f);
        float4 o1 = make_float4(msum[4] / 100.f, msum[5] / 100.f,
                                msum[6] / 100.f, msum[7] / 100.f);
        *(float4*)&xp[(size_t)b * 256 + col0]     = o0;
        *(float4*)&xp[(size_t)b * 256 + col0 + 4] = o1;
    }
}

// ------------------------------------------------------------------
// Kernel 2: FUSED fc3..fc6 MLP + persistent LSTM + fc10 + top-8.
// v14: k_mlp folded into k_lstm's prologue. Both used 512 blocks x 8
// rows with identical row maps, so the merge is mechanical:
//  - fc6 writes its 8x32 output DIRECTLY into the lstm's xs LDS array
//    (zz global round-trip removed);
//  - each block enters its recurrence as soon as ITS rows are done —
//    the device-wide barrier between the old kernels (every lstm block
//    waited on the LAST mlp block) is gone;
//  - LDS is a phase-disjoint overlay (61.7KB): mlp arrays are dead
//    before lstm arrays are written. wlds overlaps h5, so it is staged
//    only AFTER the post-fc6 barrier.
// LSTM body = R11-validated v12 (layer W staged in LDS, v10 lane tile).
// ------------------------------------------------------------------
__global__ __launch_bounds__(256) void k_mlpstm(
    const float* __restrict__ cin, const float* __restrict__ xp,
    const float* __restrict__ w3, const float* __restrict__ b3,
    const float* __restrict__ w4, const float* __restrict__ b4,
    const float* __restrict__ w5, const float* __restrict__ b5,
    const float* __restrict__ w6, const float* __restrict__ b6,
    const float* __restrict__ hid0, const float* __restrict__ cel0,
    const float* __restrict__ wih, const float* __restrict__ whh,
    const float* __restrict__ bih, const float* __restrict__ bhh,
    const float* __restrict__ w10, const float* __restrict__ b10,
    int* __restrict__ out)
{
    // ---- LDS overlay (61728 B total) ----
    // mlp phase:  in0 @0 (10240) | h3 @10240 (16384) | h4 @26624 (8192)
    //             | h5 @34816 (4096)                       [ends 38912]
    // lstm phase: xs @0 (1024) | hs @1024 (6144) | cs @7168 (6144)
    //             | gates @13312 (4096) | logits @17408 (11552)
    //             | wldsI @28960 (16384) | wldsH @45344 (16384)
    __shared__ __align__(16) float smem[15432];
    float (*in0)[320]    = (float(*)[320])(smem);
    float (*h3)[512]     = (float(*)[512])(smem + 2560);
    float (*h4)[256]     = (float(*)[256])(smem + 6656);
    float (*h5)[128]     = (float(*)[128])(smem + 8704);
    float (*xs)[32]      = (float(*)[32])(smem);
    float (*hs)[8][32]   = (float(*)[8][32])(smem + 256);
    float (*cs)[8][32]   = (float(*)[8][32])(smem + 1792);
    float (*gates)[128]  = (float(*)[128])(smem + 3328);
    float (*logits)[361] = (float(*)[361])(smem + 4352);
    float* wldsI         = smem + 7240;
    float* wldsH         = smem + 11336;

    const int tid  = threadIdx.x;
    const int row0 = blockIdx.x * 8;
    const int lane = tid & 63, wv = tid >> 6;

    // ================= MLP phase (old k_mlp, fc6 -> xs) =================
    for (int i = tid; i < 8 * 16; i += 256) {
        int r = i >> 4, q = i & 15;
        *(float4*)&in0[r][q * 4] = *(const float4*)&cin[(size_t)(row0 + r) * 64 + q * 4];
    }
    for (int i = tid; i < 8 * 64; i += 256) {
        int r = i >> 6, q = i & 63;
        *(float4*)&in0[r][64 + q * 4] = *(const float4*)&xp[(size_t)(row0 + r) * 256 + q * 4];
    }
    __syncthreads();

    {   // fc3: 320 -> 512, thread covers cols {tid, tid+256}
        float a0[8], a1[8];
        #pragma unroll
        for (int r = 0; r < 8; ++r) { a0[r] = 0.f; a1[r] = 0.f; }
        const int c0 = tid, c1 = tid + 256;
        for (int kq = 0; kq < 80; ++kq) {
            const int k0 = kq * 4;
            float wa0 = w3[(k0+0)*512 + c0], wa1 = w3[(k0+1)*512 + c0];
            float wa2 = w3[(k0+2)*512 + c0], wa3 = w3[(k0+3)*512 + c0];
            float wb0 = w3[(k0+0)*512 + c1], wb1 = w3[(k0+1)*512 + c1];
            float wb2 = w3[(k0+2)*512 + c1], wb3 = w3[(k0+3)*512 + c1];
            #pragma unroll
            for (int r = 0; r < 8; ++r) {
                const float4 a = *(const float4*)&in0[r][k0];
                a0[r] = fmaf(a.x, wa0, fmaf(a.y, wa1, fmaf(a.z, wa2, fmaf(a.w, wa3, a0[r]))));
                a1[r] = fmaf(a.x, wb0, fmaf(a.y, wb1, fmaf(a.z, wb2, fmaf(a.w, wb3, a1[r]))));
            }
        }
        const float bb0 = b3[c0], bb1 = b3[c1];
        #pragma unroll
        for (int r = 0; r < 8; ++r) {
            h3[r][c0] = fmaxf(a0[r] + bb0, 0.f);
            h3[r][c1] = fmaxf(a1[r] + bb1, 0.f);
        }
    }
    __syncthreads();

    {   // fc4: 512 -> 256
        float ac[8];
        #pragma unroll
        for (int r = 0; r < 8; ++r) ac[r] = 0.f;
        for (int kq = 0; kq < 128; ++kq) {
            const int k0 = kq * 4;
            float w0 = w4[(k0+0)*256 + tid], w1v = w4[(k0+1)*256 + tid];
            float w2v = w4[(k0+2)*256 + tid], w3v = w4[(k0+3)*256 + tid];
            #pragma unroll
            for (int r = 0; r < 8; ++r) {
                const float4 a = *(const float4*)&h3[r][k0];
                ac[r] = fmaf(a.x, w0, fmaf(a.y, w1v, fmaf(a.z, w2v, fmaf(a.w, w3v, ac[r]))));
            }
        }
        const float bb = b4[tid];
        #pragma unroll
        for (int r = 0; r < 8; ++r) h4[r][tid] = fmaxf(ac[r] + bb, 0.f);
    }
    __syncthreads();

    {   // fc5: 256 -> 128
        const int c5 = tid & 127, half = tid >> 7;
        float ac[4];
        #pragma unroll
        for (int r = 0; r < 4; ++r) ac[r] = 0.f;
        for (int kq = 0; kq < 64; ++kq) {
            const int k0 = kq * 4;
            float w0 = w5[(k0+0)*128 + c5], w1v = w5[(k0+1)*128 + c5];
            float w2v = w5[(k0+2)*128 + c5], w3v = w5[(k0+3)*128 + c5];
            #pragma unroll
            for (int r = 0; r < 4; ++r) {
                const float4 a = *(const float4*)&h4[half * 4 + r][k0];
                ac[r] = fmaf(a.x, w0, fmaf(a.y, w1v, fmaf(a.z, w2v, fmaf(a.w, w3v, ac[r]))));
            }
        }
        const float bb = b5[c5];
        #pragma unroll
        for (int r = 0; r < 4; ++r) h5[half * 4 + r][c5] = fmaxf(ac[r] + bb, 0.f);
    }
    __syncthreads();

    {   // fc6: 128 -> 32, write straight into xs (aliases dead in0[0..255])
        const int c6 = tid & 31, r = tid >> 5;
        float ac = 0.f;
        for (int kq = 0; kq < 32; ++kq) {
            const int k0 = kq * 4;
            float w0 = w6[(k0+0)*32 + c6], w1v = w6[(k0+1)*32 + c6];
            float w2v = w6[(k0+2)*32 + c6], w3v = w6[(k0+3)*32 + c6];
            const float4 a = *(const float4*)&h5[r][k0];
            ac = fmaf(a.x, w0, fmaf(a.y, w1v, fmaf(a.z, w2v, fmaf(a.w, w3v, ac))));
        }
        xs[r][c6] = fmaxf(ac + b6[c6], 0.f);
    }
    __syncthreads();   // mlp arrays (h3/h4/h5) dead past this point

    // ================= LSTM phase (v12 body) =================
    stage_panel16(wih, wldsI, 0, wv, lane);
    stage_panel16(whh, wldsH, 0, wv, lane);

    for (int i = tid; i < 6 * 8 * 32; i += 256) {
        int l = i >> 8, rj = i & 255;
        (&hs[0][0][0])[i] = hid0[(size_t)l * BATCH * 32 + (size_t)row0 * 32 + rj];
        (&cs[0][0][0])[i] = cel0[(size_t)l * BATCH * 32 + (size_t)row0 * 32 + rj];
    }
    __syncthreads();   // state visible + layer-0 W staged

    const int g  = tid & 127, rg = tid >> 7;
    const int jc = tid & 31,  jr = tid >> 5;

    for (int t = 0; t < 24; ++t) {
        for (int l = 0; l < 6; ++l) {
            const float* inp = (l == 0) ? ((t == 0) ? &xs[0][0] : &hs[5][0][0])
                                        : &hs[l - 1][0][0];
            const float bsum = bih[l * 128 + g] + bhh[l * 128 + g];
            float acc[4] = {bsum, bsum, bsum, bsum};
            #pragma unroll
            for (int k = 0; k < 32; k += 4) {
                float wi0 = wldsI[(k+0)*128 + g], wi1 = wldsI[(k+1)*128 + g];
                float wi2 = wldsI[(k+2)*128 + g], wi3 = wldsI[(k+3)*128 + g];
                float wh0 = wldsH[(k+0)*128 + g], wh1 = wldsH[(k+1)*128 + g];
                float wh2 = wldsH[(k+2)*128 + g], wh3 = wldsH[(k+3)*128 + g];
                #pragma unroll
                for (int rr = 0; rr < 4; ++rr) {
                    const int r = rg * 4 + rr;
                    const float4 ai = *(const float4*)&inp[r * 32 + k];
                    const float4 ah = *(const float4*)&hs[l][r][k];
                    acc[rr] = fmaf(ai.x, wi0, acc[rr]); acc[rr] = fmaf(ai.y, wi1, acc[rr]);
                    acc[rr] = fmaf(ai.z, wi2, acc[rr]); acc[rr] = fmaf(ai.w, wi3, acc[rr]);
                    acc[rr] = fmaf(ah.x, wh0, acc[rr]); acc[rr] = fmaf(ah.y, wh1, acc[rr]);
                    acc[rr] = fmaf(ah.z, wh2, acc[rr]); acc[rr] = fmaf(ah.w, wh3, acc[rr]);
                }
            }
            #pragma unroll
            for (int rr = 0; rr < 4; ++rr) gates[rg * 4 + rr][g] = acc[rr];
            __syncthreads();   // all wlds reads done + gates visible

            {
                const int ln = (l + 1) % 6;
                stage_panel16(wih, wldsI, ln, wv, lane);
                stage_panel16(whh, wldsH, ln, wv, lane);
            }

            {
                const float gi = gates[jr][jc],      gf = gates[jr][32 + jc];
                const float gg = gates[jr][64 + jc], go = gates[jr][96 + jc];
                const float i_ = 1.f / (1.f + expf(-gi));
                const float f_ = 1.f / (1.f + expf(-gf));
                const float o_ = 1.f / (1.f + expf(-go));
                const float g_ = tanhf(gg);
                const float cn = f_ * cs[l][jr][jc] + i_ * g_;
                cs[l][jr][jc] = cn;
                hs[l][jr][jc] = o_ * tanhf(cn);
            }
            __syncthreads();   // h/c visible + next-layer W staged
        }

        // ---- fc10 (w10: [k][361], L2-hot; runs 24x not 144x)
        #pragma unroll
        for (int pass = 0; pass < 2; ++pass) {
            const int v = tid + pass * 256;
            if (v < 361) {
                const float bb = b10[v];
                float a8[8];
                #pragma unroll
                for (int r = 0; r < 8; ++r) a8[r] = bb;
                #pragma unroll
                for (int k = 0; k < 32; k += 4) {
                    float w0 = w10[(k+0)*361 + v], w1v = w10[(k+1)*361 + v];
                    float w2v = w10[(k+2)*361 + v], w3v = w10[(k+3)*361 + v];
                    #pragma unroll
                    for (int r = 0; r < 8; ++r) {
                        const float4 a = *(const float4*)&hs[5][r][k];
                        a8[r] = fmaf(a.x, w0, fmaf(a.y, w1v, fmaf(a.z, w2v, fmaf(a.w, w3v, a8[r]))));
                    }
                }
                #pragma unroll
                for (int r = 0; r < 8; ++r) logits[r][v] = a8[r];
            }
        }
        __syncthreads();

        // ---- top-8 per row; one wave handles 2 rows.
        for (int rr = 0; rr < 2; ++rr) {
            const int r = wv * 2 + rr;
            float val[6];
            #pragma unroll
            for (int s = 0; s < 6; ++s) {
                const int v = lane + 64 * s;
                val[s] = (v < 361) ? logits[r][v] : -3.4e38f;
            }
            unsigned msk = 0x3Fu;
            const int rowg = row0 + r;
            for (int sel = 0; sel < 8; ++sel) {
                float bv = -3.4e38f; int bi = 0x7FFFFFFF;
                #pragma unroll
                for (int s = 0; s < 6; ++s) {
                    if (msk & (1u << s)) {
                        const float v2 = val[s]; const int i2 = lane + 64 * s;
                        if (v2 > bv || (v2 == bv && i2 < bi)) { bv = v2; bi = i2; }
                    }
                }
                #pragma unroll
                for (int off = 32; off >= 1; off >>= 1) {
                    const float ov = __shfl_xor(bv, off, 64);
                    const int   oi = __shfl_xor(bi, off, 64);
                    if (ov > bv || (ov == bv && oi < bi)) { bv = ov; bi = oi; }
                }
                if ((bi & 63) == lane) msk &= ~(1u << (bi >> 6));
                if (lane == 0) out[(size_t)rowg * 192 + t * 8 + sel] = bi;
            }
        }
        __syncthreads();
    }
}

// ------------------------------------------------------------------
extern "C" void kernel_launch(void* const* d_in, const int* in_sizes, int n_in,
                              void* d_out, int out_size, void* d_ws, size_t ws_size,
                              hipStream_t stream) {
    const float* cin  = (const float*)d_in[0];
    const float* x    = (const float*)d_in[1];
    const float* hid0 = (const float*)d_in[2];
    const float* cel0 = (const float*)d_in[3];
    const float* w1 = (const float*)d_in[4];  const float* b1 = (const float*)d_in[5];
    const float* w2 = (const float*)d_in[6];  const float* b2 = (const float*)d_in[7];
    const float* w3 = (const float*)d_in[8];  const float* b3 = (const float*)d_in[9];
    const float* w4 = (const float*)d_in[10]; const float* b4 = (const float*)d_in[11];
    const float* w5 = (const float*)d_in[12]; const float* b5 = (const float*)d_in[13];
    const float* w6 = (const float*)d_in[14]; const float* b6 = (const float*)d_in[15];
    const float* wih = (const float*)d_in[16]; const float* whh = (const float*)d_in[17];
    const float* bih = (const float*)d_in[18]; const float* bhh = (const float*)d_in[19];
    const float* w10 = (const float*)d_in[20]; const float* b10 = (const float*)d_in[21];

    float* xp  = (float*)d_ws;                      // 4096 x 256
    int*   out = (int*)d_out;

    k_encoder<<<BATCH, 256, 0, stream>>>(x, w1, b1, w2, b2, xp);
    k_mlpstm<<<BATCH / 8, 256, 0, stream>>>(cin, xp, w3, b3, w4, b4, w5, b5, w6, b6,
                                            hid0, cel0, wih, whh, bih, bhh, w10, b10, out);
}